// Round 8
// baseline (272.984 us; speedup 1.0000x reference)
//
#include <hip/hip_runtime.h>

typedef unsigned short u16;
typedef unsigned int u32;
typedef __attribute__((ext_vector_type(8))) short short8;
typedef __attribute__((ext_vector_type(4))) short short4_t;
typedef __attribute__((ext_vector_type(4))) float f32x4;

__device__ __forceinline__ float bf2f(u16 u){ return __uint_as_float(((u32)u)<<16); }
__device__ __forceinline__ u16 f2bf(float f){ u32 x = __float_as_uint(f); return (u16)((x + 0x7FFFu + ((x>>16)&1u)) >> 16); }

// ---------------- workspace layout (bytes) ----------------
#define OFF_FLAG   ((size_t)0)
#define OFF_COUNTS ((size_t)256)
#define OFF_POS    ((size_t)4096)                    // 16384 int
#define OFF_INV    (OFF_POS + (size_t)65536)         // 16384 int
#define OFF_OFFS   (OFF_INV + (size_t)65536)         // 32 int
#define OFF_CURS   (OFF_OFFS + (size_t)256)          // 32 int
#define OFF_XN     ((size_t)(1<<20))
#define OFF_CTXN   (OFF_XN    + (size_t)67108864)
#define OFF_WQT    (OFF_CTXN  + (size_t)4194304)
#define OFF_WKVT   (OFF_WQT   + (size_t)2097152)
#define OFF_WOUTT  (OFF_WKVT  + (size_t)2097152)
#define OFF_Q      (OFF_WOUTT + (size_t)2097152)
#define OFF_KV     (OFF_Q     + (size_t)16777216)
#define OFF_ATTN   (OFF_KV    + (size_t)4194304)
#define OFF_VT     (OFF_ATTN  + (size_t)16777216)
#define WS_NEEDED  (OFF_VT    + (size_t)2097152)

// ---------------- prep: detect int64, zero counts/cursor ----------------
__global__ void prep_kernel(const int* __restrict__ ml32, int* __restrict__ flag,
                            int* __restrict__ counts, int* __restrict__ cursor){
  int t = threadIdx.x;
  if (t < 32) counts[t] = 0;
  if (t >= 32 && t < 64) cursor[t-32] = 0;
  __shared__ int nz;
  if (t == 0) nz = 0;
  __syncthreads();
  // sample 2048 entries: if int64, odd int32 words are zero high-halves
  int odd = 0;
  #pragma unroll
  for (int k=0;k<8;++k){ int i = t + k*256; if (ml32[2*i+1] != 0) odd = 1; }
  if (odd) atomicAdd(&nz, 1);
  __syncthreads();
  if (t == 0) flag[0] = (nz == 0) ? 1 : 0;
}

// ---------------- count queries per (batch, image) ----------------
__global__ void count_kernel(const int* __restrict__ ml32, const int* __restrict__ flag,
                             int* __restrict__ counts){
  int i = blockIdx.x*256 + threadIdx.x;
  int loc = flag[0] ? ml32[2*i] : ml32[i];
  atomicAdd(&counts[(i>>12)*8 + loc], 1);
}

// ---------------- build sort permutation pos/inv + offsets ----------------
__global__ void place_kernel(const int* __restrict__ ml32, const int* __restrict__ flag,
                             const int* __restrict__ counts, int* __restrict__ cursor,
                             int* __restrict__ pos, int* __restrict__ inv, int* __restrict__ offsets){
  __shared__ int offs[32];
  int tid = threadIdx.x;
  if (tid == 0){
    int a = 0;
    for (int j=0;j<32;++j){ offs[j] = a; a += counts[j]; }
  }
  __syncthreads();
  int i = blockIdx.x*256 + tid;
  int loc = flag[0] ? ml32[2*i] : ml32[i];
  int bl = (i>>12)*8 + loc;
  int rank = atomicAdd(&cursor[bl], 1);
  int srow = offs[bl] + rank;
  pos[i] = srow;
  inv[srow] = i;
  if (blockIdx.x == 0 && tid < 32) offsets[tid] = offs[tid];
}

// ---------------- fused LayerNorm -> bf16 ----------------
template<int D>
__global__ __launch_bounds__(256) void ln_bf16(const float* __restrict__ x, const float* __restrict__ w,
                                               const float* __restrict__ b, u16* __restrict__ out){
  constexpr int VEC = D/256;
  int row = blockIdx.x;
  const float* xr = x + (size_t)row*D;
  int tid = threadIdx.x;
  float v[VEC];
  #pragma unroll
  for (int i=0;i<VEC;i+=4){
    f32x4 f = *(const f32x4*)(xr + tid*VEC + i);
    v[i]=f[0]; v[i+1]=f[1]; v[i+2]=f[2]; v[i+3]=f[3];
  }
  float s=0.f, sq=0.f;
  #pragma unroll
  for (int i=0;i<VEC;++i){ s += v[i]; sq += v[i]*v[i]; }
  #pragma unroll
  for (int off=32;off;off>>=1){ s += __shfl_xor(s,off,64); sq += __shfl_xor(sq,off,64); }
  __shared__ float red[8];
  int lane = tid&63, wid = tid>>6;
  if (lane==0){ red[wid]=s; red[4+wid]=sq; }
  __syncthreads();
  s  = red[0]+red[1]+red[2]+red[3];
  sq = red[4]+red[5]+red[6]+red[7];
  float mu = s/(float)D;
  float var = sq/(float)D - mu*mu;
  float rs = rsqrtf(var + 1e-5f);
  u16 o[VEC];
  #pragma unroll
  for (int i=0;i<VEC;i+=4){
    f32x4 wv = *(const f32x4*)(w + tid*VEC + i);
    f32x4 bv = *(const f32x4*)(b + tid*VEC + i);
    #pragma unroll
    for (int u=0;u<4;++u) o[i+u] = f2bf((v[i+u]-mu)*rs*wv[u] + bv[u]);
  }
  if constexpr (VEC==8) *(short8*)(out + (size_t)row*D + tid*8) = *(short8*)o;
  else                  *(short4_t*)(out + (size_t)row*D + tid*4) = *(short4_t*)o;
}

// ---------------- merged weight transposes f32 [K][N] -> bf16 [N][K] ----------------
// 3072 blocks: [0,1024) Wq 2048x512, [1024,2048) Wkv 1024x1024, [2048,3072) Wout 512x2048
__global__ __launch_bounds__(256) void transpose_all(const float* __restrict__ Wq, const float* __restrict__ Wkv,
                                                     const float* __restrict__ Wout, u16* __restrict__ WqT,
                                                     u16* __restrict__ WkvT, u16* __restrict__ WoutT){
  __shared__ float t[32][33];
  int id = blockIdx.x;
  const float* in; u16* out; int K, N, tile, tx_n;
  if (id < 1024)      { in=Wq;   out=WqT;   K=2048; N=512;  tile=id;      tx_n=16; }
  else if (id < 2048) { in=Wkv;  out=WkvT;  K=1024; N=1024; tile=id-1024; tx_n=32; }
  else                { in=Wout; out=WoutT; K=512;  N=2048; tile=id-2048; tx_n=64; }
  int n0 = (tile % tx_n)*32, k0 = (tile / tx_n)*32;
  int tx = threadIdx.x & 31, ty = threadIdx.x >> 5;
  #pragma unroll
  for (int r=0;r<32;r+=8) t[ty+r][tx] = in[(size_t)(k0+ty+r)*N + n0+tx];
  __syncthreads();
  #pragma unroll
  for (int r=0;r<32;r+=8) out[(size_t)(n0+ty+r)*K + k0+tx] = f2bf(t[tx][ty+r]);
}

// ---------------- bf16 GEMM: C[M,N] = A[M,K] * B^T  (B stored [N][K]) ----------------
// MODE: 0 = f32 out dense, 1 = bf16 out dense,
//       2 = bf16 out scaled 0.125, rows permuted by perm (Q-GEMM)
//       3 = KV: cols<512 -> bf16 kvbuf; cols>=512 -> V transposed into vt[bl][h][d][key]
template<int MODE>
__global__ __launch_bounds__(256) void gemm_bt(const u16* __restrict__ A, const u16* __restrict__ B,
                                               void* __restrict__ Cv, int M, int N, int K,
                                               const int* __restrict__ perm, u16* __restrict__ vtp){
  __shared__ __align__(16) u16 lds[2][2][128*32];
  int tid = threadIdx.x, lane = tid&63, wid = tid>>6;
  int nbn = N>>7;
  int nwg = gridDim.x;
  int wg = blockIdx.x;
  int cpx = nwg>>3;                 // all grids here are %8==0 -> bijective XCD swizzle
  wg = (wg&7)*cpx + (wg>>3);
  int brow = wg/nbn, bcol = wg%nbn;

  auto stage = [&](int buf, int kt){
    #pragma unroll
    for (int i=0;i<2;++i){
      int cb = i*256 + wid*64;      // wave-uniform chunk base
      int c  = cb + lane;
      int row = c>>2, kc = c&3;
      const u16* ga = A + (size_t)(brow*128+row)*K + kt*32 + kc*8;
      __builtin_amdgcn_global_load_lds((const __attribute__((address_space(1))) u32*)ga,
          (__attribute__((address_space(3))) u32*)&lds[buf][0][cb*8], 16, 0, 0);
      const u16* gb = B + (size_t)(bcol*128+row)*K + kt*32 + kc*8;
      __builtin_amdgcn_global_load_lds((const __attribute__((address_space(1))) u32*)gb,
          (__attribute__((address_space(3))) u32*)&lds[buf][1][cb*8], 16, 0, 0);
    }
  };

  int wm = wid>>1, wn = wid&1;
  f32x4 acc[4][4] = {};
  int nkt = K>>5;
  stage(0,0);
  __syncthreads();
  for (int kt=0; kt<nkt; ++kt){
    int cur = kt&1;
    if (kt+1<nkt) stage(cur^1, kt+1);
    short8 af[4], bfr[4];
    int r = lane&15, kq = lane>>4;
    #pragma unroll
    for (int mi=0;mi<4;++mi) af[mi]  = *(const short8*)&lds[cur][0][(wm*64+mi*16+r)*32 + kq*8];
    #pragma unroll
    for (int ni=0;ni<4;++ni) bfr[ni] = *(const short8*)&lds[cur][1][(wn*64+ni*16+r)*32 + kq*8];
    #pragma unroll
    for (int mi=0;mi<4;++mi)
      #pragma unroll
      for (int ni=0;ni<4;++ni)
        acc[mi][ni] = __builtin_amdgcn_mfma_f32_16x16x32_bf16(af[mi], bfr[ni], acc[mi][ni], 0,0,0);
    __syncthreads();
  }
  int r4 = (lane>>4)*4, cc = lane&15;
  #pragma unroll
  for (int mi=0;mi<4;++mi){
    int rowb = brow*128 + wm*64 + mi*16 + r4;
    int prow[4];
    #pragma unroll
    for (int rr=0;rr<4;++rr) prow[rr] = (MODE==2) ? perm[rowb+rr] : (rowb+rr);
    #pragma unroll
    for (int ni=0;ni<4;++ni){
      int col = bcol*128 + wn*64 + ni*16 + cc;
      #pragma unroll
      for (int rr=0;rr<4;++rr){
        float val = acc[mi][ni][rr];
        if (MODE==0)      ((float*)Cv)[(size_t)prow[rr]*N+col] = val;
        else if (MODE==1) ((u16*)Cv)[(size_t)prow[rr]*N+col] = f2bf(val);
        else if (MODE==2) ((u16*)Cv)[(size_t)prow[rr]*N+col] = f2bf(val*0.125f);
        else {
          if (col < 512)  ((u16*)Cv)[(size_t)prow[rr]*N+col] = f2bf(val);
          else {
            int row = rowb + rr;
            int hv = (col-512)>>6, d = (col-512)&63;
            vtp[(size_t)((row>>6)*8 + hv)*4096 + d*64 + (row&63)] = f2bf(val);
          }
        }
      }
    }
  }
}

// ---------------- MFMA bucketed attention, v4: dense gather + indexed scatter ----------------
// grid (chunk=128, bucket=32), block 512 = 8 waves = 8 heads; 32 sorted queries/block.
// Q rows CONTIGUOUS in qb (bucket-major, permuted by Q-GEMM). O scattered back to
// ORIGINAL row order via inv (wave-per-row, 1KB contiguous per row). Q pre-scaled 0.125.
__global__ __launch_bounds__(512) void attn_mfma4(const u16* __restrict__ qb, const u16* __restrict__ kvb,
                                                  const u16* __restrict__ vt, u16* __restrict__ ob,
                                                  const int* __restrict__ counts, const int* __restrict__ offsets,
                                                  const int* __restrict__ inv){
  int bl = blockIdx.y, chunk = blockIdx.x;
  int cnt = counts[bl];
  if (chunk*32 >= cnt) return;
  int base_s = offsets[bl] + chunk*32;
  int nvalid = cnt - chunk*32; if (nvalid > 32) nvalid = 32;
  int b = bl>>3, loc = bl&7;
  int tid = threadIdx.x, lane = tid&63, h = tid>>6;   // wave id == head
  __shared__ u16 qs[32][520];      // sorted Q rows; reused for O staging
  __shared__ u16 plds[8][32][72];  // per-wave P tile
  __shared__ int qi[32];           // original row index for scatter

  if (tid < 32)
    qi[tid] = (tid < nvalid) ? inv[base_s + tid] : -1;

  // ---- dense coalesced gather: 32 contiguous rows ----
  const u16* qsrc = qb + (size_t)base_s*512;
  #pragma unroll
  for (int p=0;p<4;++p){
    int c = p*512 + tid;           // 2048 chunks of 16B
    int row = c>>6, cc = c&63;
    if (base_s + row < 16384)
      *(short8*)&qs[row][cc*8] = *(const short8*)(qsrc + (size_t)row*512 + cc*8);
  }
  __syncthreads();

  int r = lane&15, g = lane>>4;

  // A-frags (Q) from LDS
  short8 qf[2][2];
  #pragma unroll
  for (int mt=0;mt<2;++mt){
    qf[mt][0] = *(const short8*)&qs[mt*16+r][h*64 + g*8];
    qf[mt][1] = *(const short8*)&qs[mt*16+r][h*64 + 32 + g*8];
  }
  __syncthreads();   // all qs reads done before O overwrites it

  // K fragments (L2-resident): key = nt*16 + r
  const u16* kbase = kvb + (size_t)(b*512 + loc*64)*1024 + h*64;
  short8 kfr[4][2];
  #pragma unroll
  for (int nt=0;nt<4;++nt){
    const u16* krow = kbase + (size_t)(nt*16 + r)*1024;
    kfr[nt][0] = *(const short8*)(krow + g*8);
    kfr[nt][1] = *(const short8*)(krow + 32 + g*8);
  }

  // QK^T
  f32x4 acc[2][4] = {};
  #pragma unroll
  for (int mt=0;mt<2;++mt)
    #pragma unroll
    for (int nt=0;nt<4;++nt){
      acc[mt][nt] = __builtin_amdgcn_mfma_f32_16x16x32_bf16(qf[mt][0], kfr[nt][0], acc[mt][nt], 0,0,0);
      acc[mt][nt] = __builtin_amdgcn_mfma_f32_16x16x32_bf16(qf[mt][1], kfr[nt][1], acc[mt][nt], 0,0,0);
    }

  // softmax per query row (row = mt*16 + g*4 + rr; 16 lanes r hold 4 key-tiles)
  #pragma unroll
  for (int mt=0;mt<2;++mt){
    #pragma unroll
    for (int rr=0;rr<4;++rr){
      float m = fmaxf(fmaxf(acc[mt][0][rr], acc[mt][1][rr]), fmaxf(acc[mt][2][rr], acc[mt][3][rr]));
      #pragma unroll
      for (int off=1;off<16;off<<=1) m = fmaxf(m, __shfl_xor(m, off));
      float e0 = __expf(acc[mt][0][rr]-m), e1 = __expf(acc[mt][1][rr]-m);
      float e2 = __expf(acc[mt][2][rr]-m), e3 = __expf(acc[mt][3][rr]-m);
      float sum = (e0+e1)+(e2+e3);
      #pragma unroll
      for (int off=1;off<16;off<<=1) sum += __shfl_xor(sum, off);
      float rs = 1.0f/sum;
      int row = mt*16 + g*4 + rr;
      plds[h][row][ 0 + r] = f2bf(e0*rs);
      plds[h][row][16 + r] = f2bf(e1*rs);
      plds[h][row][32 + r] = f2bf(e2*rs);
      plds[h][row][48 + r] = f2bf(e3*rs);
    }
  }

  // V fragments from vt [bl][h][d][key]
  const u16* vbase = vt + (size_t)(bl*8 + h)*4096;
  short8 vf[2][4];
  #pragma unroll
  for (int nt=0;nt<4;++nt){
    const u16* vrow = vbase + (size_t)(nt*16 + r)*64;
    vf[0][nt] = *(const short8*)(vrow + g*8);
    vf[1][nt] = *(const short8*)(vrow + 32 + g*8);
  }

  // PV
  f32x4 oacc[2][4] = {};
  #pragma unroll
  for (int mt=0;mt<2;++mt){
    short8 pa0 = *(const short8*)&plds[h][mt*16 + r][g*8];
    short8 pa1 = *(const short8*)&plds[h][mt*16 + r][32 + g*8];
    #pragma unroll
    for (int nt=0;nt<4;++nt){
      oacc[mt][nt] = __builtin_amdgcn_mfma_f32_16x16x32_bf16(pa0, vf[0][nt], oacc[mt][nt], 0,0,0);
      oacc[mt][nt] = __builtin_amdgcn_mfma_f32_16x16x32_bf16(pa1, vf[1][nt], oacc[mt][nt], 0,0,0);
    }
  }

  // stage O into qs (C layout: col d = nt*16 + r, row = mt*16 + g*4 + rr)
  #pragma unroll
  for (int mt=0;mt<2;++mt)
    #pragma unroll
    for (int rr=0;rr<4;++rr){
      int row = mt*16 + g*4 + rr;
      #pragma unroll
      for (int nt=0;nt<4;++nt)
        qs[row][h*64 + nt*16 + r] = f2bf(oacc[mt][nt][rr]);
    }
  __syncthreads();

  // ---- indexed scatter to ORIGINAL rows: wave-per-row, 1KB contiguous ----
  #pragma unroll
  for (int p=0;p<4;++p){
    int c = p*512 + tid;
    int row = c>>6, cc = c&63;
    int qq = qi[row];
    if (qq >= 0)
      *(short8*)(ob + (size_t)qq*512 + cc*8) = *(const short8*)&qs[row][cc*8];
  }
}

extern "C" void kernel_launch(void* const* d_in, const int* in_sizes, int n_in,
                              void* d_out, int out_size, void* d_ws, size_t ws_size,
                              hipStream_t stream) {
  const float* x    = (const float*)d_in[0];
  const float* ctx  = (const float*)d_in[1];
  const int*   ml   = (const int*)d_in[2];
  const float* nw   = (const float*)d_in[3];
  const float* nb   = (const float*)d_in[4];
  const float* ncw  = (const float*)d_in[5];
  const float* ncb  = (const float*)d_in[6];
  const float* Wq   = (const float*)d_in[7];
  const float* Wkv  = (const float*)d_in[8];
  const float* Wout = (const float*)d_in[9];
  float* out = (float*)d_out;
  char* ws = (char*)d_ws;
  if (ws_size < WS_NEEDED) return;   // fail loudly (output stays poisoned)

  int* flag    = (int*)(ws + OFF_FLAG);
  int* counts  = (int*)(ws + OFF_COUNTS);
  int* pos     = (int*)(ws + OFF_POS);
  int* inv     = (int*)(ws + OFF_INV);
  int* offsets = (int*)(ws + OFF_OFFS);
  int* cursor  = (int*)(ws + OFF_CURS);
  u16* xn     = (u16*)(ws + OFF_XN);
  u16* ctxn   = (u16*)(ws + OFF_CTXN);
  u16* WqT    = (u16*)(ws + OFF_WQT);
  u16* WkvT   = (u16*)(ws + OFF_WKVT);
  u16* WoutT  = (u16*)(ws + OFF_WOUTT);
  u16* qbuf   = (u16*)(ws + OFF_Q);
  u16* kvbuf  = (u16*)(ws + OFF_KV);
  u16* attn_o = (u16*)(ws + OFF_ATTN);
  u16* vtbuf  = (u16*)(ws + OFF_VT);

  prep_kernel<<<1,256,0,stream>>>(ml, flag, counts, cursor);
  count_kernel<<<64,256,0,stream>>>(ml, flag, counts);
  place_kernel<<<64,256,0,stream>>>(ml, flag, counts, cursor, pos, inv, offsets);
  ln_bf16<2048><<<16384,256,0,stream>>>(x,   nw,  nb,  xn);
  ln_bf16<1024><<<2048, 256,0,stream>>>(ctx, ncw, ncb, ctxn);
  transpose_all<<<3072, 256,0,stream>>>(Wq, Wkv, Wout, WqT, WkvT, WoutT);
  gemm_bt<2><<<512, 256,0,stream>>>(xn,   WqT,  qbuf,  16384, 512,  2048, pos, nullptr);     // Q scaled+sorted
  gemm_bt<3><<<128, 256,0,stream>>>(ctxn, WkvT, kvbuf, 2048,  1024, 1024, nullptr, vtbuf);   // KV + fused V^T
  attn_mfma4<<<dim3(128,32),512,0,stream>>>(qbuf, kvbuf, vtbuf, attn_o, counts, offsets, inv);
  gemm_bt<0><<<2048,256,0,stream>>>(attn_o, WoutT, out, 16384, 2048, 512, nullptr, nullptr); // dense
}

// Round 9
// 241.544 us; speedup vs baseline: 1.1302x; 1.1302x over previous
//
#include <hip/hip_runtime.h>

typedef unsigned short u16;
typedef unsigned int u32;
typedef __attribute__((ext_vector_type(8))) short short8;
typedef __attribute__((ext_vector_type(4))) short short4_t;
typedef __attribute__((ext_vector_type(4))) float f32x4;

__device__ __forceinline__ float bf2f(u16 u){ return __uint_as_float(((u32)u)<<16); }
__device__ __forceinline__ u16 f2bf(float f){ u32 x = __float_as_uint(f); return (u16)((x + 0x7FFFu + ((x>>16)&1u)) >> 16); }

// ---------------- workspace layout (bytes) ----------------
#define OFF_FLAG   ((size_t)0)
#define OFF_COUNTS ((size_t)256)
#define OFF_LISTS  ((size_t)4096)                    // 32*4096 int
#define OFF_XN     ((size_t)(1<<20))
#define OFF_CTXN   (OFF_XN    + (size_t)67108864)
#define OFF_WQT    (OFF_CTXN  + (size_t)4194304)
#define OFF_WKVT   (OFF_WQT   + (size_t)2097152)
#define OFF_WOUTT  (OFF_WKVT  + (size_t)2097152)
#define OFF_Q      (OFF_WOUTT + (size_t)2097152)
#define OFF_KV     (OFF_Q     + (size_t)16777216)
#define OFF_ATTN   (OFF_KV    + (size_t)4194304)
#define OFF_VT     (OFF_ATTN  + (size_t)16777216)
#define WS_NEEDED  (OFF_VT    + (size_t)2097152)

// ---------------- prep: detect int64 + zero bucket counts ----------------
__global__ void prep_kernel(const int* __restrict__ ml32, int* __restrict__ flag, int* __restrict__ counts){
  int t = threadIdx.x;
  if (t < 32) counts[t] = 0;
  __shared__ int nz;
  if (t == 0) nz = 0;
  __syncthreads();
  if (t < 128 && ml32[2*t+1] != 0) atomicAdd(&nz, 1);
  __syncthreads();
  if (t == 0) flag[0] = (nz == 0) ? 1 : 0;
}

// ---------------- fused LayerNorm -> bf16 ----------------
template<int D>
__global__ __launch_bounds__(256) void ln_bf16(const float* __restrict__ x, const float* __restrict__ w,
                                               const float* __restrict__ b, u16* __restrict__ out){
  constexpr int VEC = D/256;
  int row = blockIdx.x;
  const float* xr = x + (size_t)row*D;
  int tid = threadIdx.x;
  float v[VEC];
  #pragma unroll
  for (int i=0;i<VEC;i+=4){
    f32x4 f = *(const f32x4*)(xr + tid*VEC + i);
    v[i]=f[0]; v[i+1]=f[1]; v[i+2]=f[2]; v[i+3]=f[3];
  }
  float s=0.f, sq=0.f;
  #pragma unroll
  for (int i=0;i<VEC;++i){ s += v[i]; sq += v[i]*v[i]; }
  #pragma unroll
  for (int off=32;off;off>>=1){ s += __shfl_xor(s,off,64); sq += __shfl_xor(sq,off,64); }
  __shared__ float red[8];
  int lane = tid&63, wid = tid>>6;
  if (lane==0){ red[wid]=s; red[4+wid]=sq; }
  __syncthreads();
  s  = red[0]+red[1]+red[2]+red[3];
  sq = red[4]+red[5]+red[6]+red[7];
  float mu = s/(float)D;
  float var = sq/(float)D - mu*mu;
  float rs = rsqrtf(var + 1e-5f);
  u16 o[VEC];
  #pragma unroll
  for (int i=0;i<VEC;i+=4){
    f32x4 wv = *(const f32x4*)(w + tid*VEC + i);
    f32x4 bv = *(const f32x4*)(b + tid*VEC + i);
    #pragma unroll
    for (int u=0;u<4;++u) o[i+u] = f2bf((v[i+u]-mu)*rs*wv[u] + bv[u]);
  }
  if constexpr (VEC==8) *(short8*)(out + (size_t)row*D + tid*8) = *(short8*)o;
  else                  *(short4_t*)(out + (size_t)row*D + tid*4) = *(short4_t*)o;
}

// ---------------- merged weight transposes f32 [K][N] -> bf16 [N][K] ----------------
__global__ __launch_bounds__(256) void transpose_all(const float* __restrict__ Wq, const float* __restrict__ Wkv,
                                                     const float* __restrict__ Wout, u16* __restrict__ WqT,
                                                     u16* __restrict__ WkvT, u16* __restrict__ WoutT){
  __shared__ float t[32][33];
  int id = blockIdx.x;
  const float* in; u16* out; int K, N, tile, tx_n;
  if (id < 1024)      { in=Wq;   out=WqT;   K=2048; N=512;  tile=id;      tx_n=16; }
  else if (id < 2048) { in=Wkv;  out=WkvT;  K=1024; N=1024; tile=id-1024; tx_n=32; }
  else                { in=Wout; out=WoutT; K=512;  N=2048; tile=id-2048; tx_n=64; }
  int n0 = (tile % tx_n)*32, k0 = (tile / tx_n)*32;
  int tx = threadIdx.x & 31, ty = threadIdx.x >> 5;
  #pragma unroll
  for (int r=0;r<32;r+=8) t[ty+r][tx] = in[(size_t)(k0+ty+r)*N + n0+tx];
  __syncthreads();
  #pragma unroll
  for (int r=0;r<32;r+=8) out[(size_t)(n0+ty+r)*K + k0+tx] = f2bf(t[tx][ty+r]);
}

// ---------------- V transpose: kv V-half [key][h*64+d] -> vt [bl][h][d][key] ----------------
__global__ __launch_bounds__(256) void transpose_v(const u16* __restrict__ kvb, u16* __restrict__ vt){
  int h = blockIdx.x, bl = blockIdx.y;
  __shared__ u16 t[64][72];
  int tid = threadIdx.x;
  const u16* src = kvb + (size_t)(bl*64)*1024 + 512 + h*64;
  #pragma unroll
  for (int i=0;i<2;++i){
    int idx = i*2048 + tid*8;
    int key = idx>>6, d = idx&63;
    *(short8*)&t[key][d] = *(const short8*)(src + (size_t)key*1024 + d);
  }
  __syncthreads();
  u16* dst = vt + (size_t)(bl*8+h)*4096;
  #pragma unroll
  for (int i=0;i<2;++i){
    int idx = i*2048 + tid*8;
    int d = idx>>6, k0 = idx&63;
    u16 tmp[8];
    #pragma unroll
    for (int u=0;u<8;++u) tmp[u] = t[k0+u][d];
    *(short8*)(dst + d*64 + k0) = *(short8*)tmp;
  }
}

// ---------------- bf16 GEMM: C[M,N] = A[M,K] * B^T  (B stored [N][K]) ----------------
// MODE: 0 = f32 out, 1 = bf16 out, 2 = bf16 out scaled by 0.125 (exact)
template<int MODE>
__global__ __launch_bounds__(256) void gemm_bt(const u16* __restrict__ A, const u16* __restrict__ B,
                                               void* __restrict__ Cv, int M, int N, int K){
  __shared__ __align__(16) u16 lds[2][2][128*32];
  int tid = threadIdx.x, lane = tid&63, wid = tid>>6;
  int nbn = N>>7;
  int nwg = gridDim.x;
  int wg = blockIdx.x;
  int cpx = nwg>>3;                 // grids %8==0 -> bijective XCD swizzle
  wg = (wg&7)*cpx + (wg>>3);
  int brow = wg/nbn, bcol = wg%nbn;

  auto stage = [&](int buf, int kt){
    #pragma unroll
    for (int i=0;i<2;++i){
      int cb = i*256 + wid*64;      // wave-uniform chunk base
      int c  = cb + lane;
      int row = c>>2, kc = c&3;
      const u16* ga = A + (size_t)(brow*128+row)*K + kt*32 + kc*8;
      __builtin_amdgcn_global_load_lds((const __attribute__((address_space(1))) u32*)ga,
          (__attribute__((address_space(3))) u32*)&lds[buf][0][cb*8], 16, 0, 0);
      const u16* gb = B + (size_t)(bcol*128+row)*K + kt*32 + kc*8;
      __builtin_amdgcn_global_load_lds((const __attribute__((address_space(1))) u32*)gb,
          (__attribute__((address_space(3))) u32*)&lds[buf][1][cb*8], 16, 0, 0);
    }
  };

  int wm = wid>>1, wn = wid&1;
  f32x4 acc[4][4] = {};
  int nkt = K>>5;
  stage(0,0);
  __syncthreads();
  for (int kt=0; kt<nkt; ++kt){
    int cur = kt&1;
    if (kt+1<nkt) stage(cur^1, kt+1);
    short8 af[4], bfr[4];
    int r = lane&15, kq = lane>>4;
    #pragma unroll
    for (int mi=0;mi<4;++mi) af[mi]  = *(const short8*)&lds[cur][0][(wm*64+mi*16+r)*32 + kq*8];
    #pragma unroll
    for (int ni=0;ni<4;++ni) bfr[ni] = *(const short8*)&lds[cur][1][(wn*64+ni*16+r)*32 + kq*8];
    #pragma unroll
    for (int mi=0;mi<4;++mi)
      #pragma unroll
      for (int ni=0;ni<4;++ni)
        acc[mi][ni] = __builtin_amdgcn_mfma_f32_16x16x32_bf16(af[mi], bfr[ni], acc[mi][ni], 0,0,0);
    __syncthreads();
  }
  int r4 = (lane>>4)*4, cc = lane&15;
  #pragma unroll
  for (int mi=0;mi<4;++mi)
    #pragma unroll
    for (int ni=0;ni<4;++ni)
      #pragma unroll
      for (int rr=0;rr<4;++rr){
        int row = brow*128 + wm*64 + mi*16 + r4 + rr;
        int col = bcol*128 + wn*64 + ni*16 + cc;
        float val = acc[mi][ni][rr];
        if (MODE==2) val *= 0.125f;
        if (MODE)  ((u16*)Cv)[(size_t)row*N+col] = f2bf(val);
        else       ((float*)Cv)[(size_t)row*N+col] = val;
      }
}

// ---------------- bucket queries by (batch, image) ----------------
__global__ void bucket_kernel(const int* __restrict__ ml32, const int* __restrict__ flag,
                              int* __restrict__ counts, int* __restrict__ lists){
  int i = blockIdx.x*256 + threadIdx.x;   // 0..16383 = b*4096+s
  int loc = flag[0] ? ml32[2*i] : ml32[i];
  int bl = (i>>12)*8 + loc;
  int pos = atomicAdd(&counts[bl], 1);
  lists[bl*4096 + pos] = i & 4095;
}

// ---------------- MFMA bucketed attention, v5: single LDS buffer, wave-private slices ----------------
// grid (chunk=128, bucket=32), block 512 = 8 waves = 8 heads; 32 queries/block.
// One 33KB LDS buffer (qs) -> 4 blocks/CU. After the cooperative gather, each wave
// touches ONLY its own 64-col head slice of qs (Q frags, then P tile, then O tile)
// -> no plds, no mid-kernel barrier. qi via broadcast lists[] reads (no LDS staging).
// Q pre-scaled by 0.125 (folded into Q-GEMM).
__global__ __launch_bounds__(512) void attn_mfma5(const u16* __restrict__ qb, const u16* __restrict__ kvb,
                                                  const u16* __restrict__ vt, u16* __restrict__ ob,
                                                  const int* __restrict__ counts, const int* __restrict__ lists){
  int bl = blockIdx.y, chunk = blockIdx.x;
  int cnt = counts[bl];
  int q0 = chunk*32;
  if (q0 >= cnt) return;
  int b = bl>>3, loc = bl&7;
  int tid = threadIdx.x, lane = tid&63, h = tid>>6;   // wave id == head
  __shared__ u16 qs[32][520];      // gathered Q rows -> per-wave P tile -> per-wave O tile
  int r = lane&15, g = lane>>4;

  // ---- K/V fragment loads issued early (independent of LDS) ----
  const u16* kbase = kvb + (size_t)(b*512 + loc*64)*1024 + h*64;
  short8 kfr[4][2];
  #pragma unroll
  for (int nt=0;nt<4;++nt){
    const u16* krow = kbase + (size_t)(nt*16 + r)*1024;
    kfr[nt][0] = *(const short8*)(krow + g*8);
    kfr[nt][1] = *(const short8*)(krow + 32 + g*8);
  }
  const u16* vbase = vt + (size_t)(bl*8 + h)*4096;
  short8 vf[2][4];
  #pragma unroll
  for (int nt=0;nt<4;++nt){
    const u16* vrow = vbase + (size_t)(nt*16 + r)*64;
    vf[0][nt] = *(const short8*)(vrow + g*8);
    vf[1][nt] = *(const short8*)(vrow + 32 + g*8);
  }

  // ---- coalesced gather: wave-per-row, qi via broadcast read (64 lanes same addr) ----
  const u16* qbase = qb + (size_t)(b*4096)*512;
  #pragma unroll
  for (int p=0;p<4;++p){
    int c = p*512 + tid;           // row=c>>6, 16B-chunk=c&63
    int row = c>>6, cc = c&63;
    int qq = (q0 + row < cnt) ? lists[bl*4096 + q0 + row] : -1;
    if (qq >= 0)
      *(short8*)&qs[row][cc*8] = *(const short8*)(qbase + (size_t)qq*512 + cc*8);
  }
  __syncthreads();

  // ---- Q frags from own head slice ----
  short8 qf[2][2];
  #pragma unroll
  for (int mt=0;mt<2;++mt){
    qf[mt][0] = *(const short8*)&qs[mt*16+r][h*64 + g*8];
    qf[mt][1] = *(const short8*)&qs[mt*16+r][h*64 + 32 + g*8];
  }

  // ---- QK^T ----
  f32x4 acc[2][4] = {};
  #pragma unroll
  for (int mt=0;mt<2;++mt)
    #pragma unroll
    for (int nt=0;nt<4;++nt){
      acc[mt][nt] = __builtin_amdgcn_mfma_f32_16x16x32_bf16(qf[mt][0], kfr[nt][0], acc[mt][nt], 0,0,0);
      acc[mt][nt] = __builtin_amdgcn_mfma_f32_16x16x32_bf16(qf[mt][1], kfr[nt][1], acc[mt][nt], 0,0,0);
    }

  // ---- softmax; P -> own slice of qs (wave-private, no barrier needed) ----
  #pragma unroll
  for (int mt=0;mt<2;++mt){
    #pragma unroll
    for (int rr=0;rr<4;++rr){
      float m = fmaxf(fmaxf(acc[mt][0][rr], acc[mt][1][rr]), fmaxf(acc[mt][2][rr], acc[mt][3][rr]));
      #pragma unroll
      for (int off=1;off<16;off<<=1) m = fmaxf(m, __shfl_xor(m, off));
      float e0 = __expf(acc[mt][0][rr]-m), e1 = __expf(acc[mt][1][rr]-m);
      float e2 = __expf(acc[mt][2][rr]-m), e3 = __expf(acc[mt][3][rr]-m);
      float sum = (e0+e1)+(e2+e3);
      #pragma unroll
      for (int off=1;off<16;off<<=1) sum += __shfl_xor(sum, off);
      float rs = 1.0f/sum;
      int row = mt*16 + g*4 + rr;
      qs[row][h*64 +  0 + r] = f2bf(e0*rs);
      qs[row][h*64 + 16 + r] = f2bf(e1*rs);
      qs[row][h*64 + 32 + r] = f2bf(e2*rs);
      qs[row][h*64 + 48 + r] = f2bf(e3*rs);
    }
  }

  // ---- PV (P frags from own slice) ----
  f32x4 oacc[2][4] = {};
  #pragma unroll
  for (int mt=0;mt<2;++mt){
    short8 pa0 = *(const short8*)&qs[mt*16 + r][h*64 + g*8];
    short8 pa1 = *(const short8*)&qs[mt*16 + r][h*64 + 32 + g*8];
    #pragma unroll
    for (int nt=0;nt<4;++nt){
      oacc[mt][nt] = __builtin_amdgcn_mfma_f32_16x16x32_bf16(pa0, vf[0][nt], oacc[mt][nt], 0,0,0);
      oacc[mt][nt] = __builtin_amdgcn_mfma_f32_16x16x32_bf16(pa1, vf[1][nt], oacc[mt][nt], 0,0,0);
    }
  }

  // ---- O -> own slice of qs (C layout: col d = nt*16 + r, row = mt*16 + g*4 + rr) ----
  #pragma unroll
  for (int mt=0;mt<2;++mt)
    #pragma unroll
    for (int rr=0;rr<4;++rr){
      int row = mt*16 + g*4 + rr;
      #pragma unroll
      for (int nt=0;nt<4;++nt)
        qs[row][h*64 + nt*16 + r] = f2bf(oacc[mt][nt][rr]);
    }
  __syncthreads();

  // ---- coalesced scatter: wave-per-row, 1KB contiguous per row ----
  #pragma unroll
  for (int p=0;p<4;++p){
    int c = p*512 + tid;
    int row = c>>6, cc = c&63;
    int qq = (q0 + row < cnt) ? lists[bl*4096 + q0 + row] : -1;
    if (qq >= 0)
      *(short8*)(ob + ((size_t)(b*4096) + qq)*512 + cc*8) = *(const short8*)&qs[row][cc*8];
  }
}

extern "C" void kernel_launch(void* const* d_in, const int* in_sizes, int n_in,
                              void* d_out, int out_size, void* d_ws, size_t ws_size,
                              hipStream_t stream) {
  const float* x    = (const float*)d_in[0];
  const float* ctx  = (const float*)d_in[1];
  const int*   ml   = (const int*)d_in[2];
  const float* nw   = (const float*)d_in[3];
  const float* nb   = (const float*)d_in[4];
  const float* ncw  = (const float*)d_in[5];
  const float* ncb  = (const float*)d_in[6];
  const float* Wq   = (const float*)d_in[7];
  const float* Wkv  = (const float*)d_in[8];
  const float* Wout = (const float*)d_in[9];
  float* out = (float*)d_out;
  char* ws = (char*)d_ws;
  if (ws_size < WS_NEEDED) return;   // fail loudly (output stays poisoned)

  int* flag   = (int*)(ws + OFF_FLAG);
  int* counts = (int*)(ws + OFF_COUNTS);
  int* lists  = (int*)(ws + OFF_LISTS);
  u16* xn     = (u16*)(ws + OFF_XN);
  u16* ctxn   = (u16*)(ws + OFF_CTXN);
  u16* WqT    = (u16*)(ws + OFF_WQT);
  u16* WkvT   = (u16*)(ws + OFF_WKVT);
  u16* WoutT  = (u16*)(ws + OFF_WOUTT);
  u16* qbuf   = (u16*)(ws + OFF_Q);
  u16* kvbuf  = (u16*)(ws + OFF_KV);
  u16* attn_o = (u16*)(ws + OFF_ATTN);
  u16* vtbuf  = (u16*)(ws + OFF_VT);

  prep_kernel<<<1,256,0,stream>>>(ml, flag, counts);
  ln_bf16<2048><<<16384,256,0,stream>>>(x,   nw,  nb,  xn);
  ln_bf16<1024><<<2048, 256,0,stream>>>(ctx, ncw, ncb, ctxn);
  transpose_all<<<3072, 256,0,stream>>>(Wq, Wkv, Wout, WqT, WkvT, WoutT);
  gemm_bt<2><<<512, 256,0,stream>>>(xn,   WqT,  qbuf,  16384, 512,  2048);  // Q, pre-scaled 0.125
  gemm_bt<1><<<128, 256,0,stream>>>(ctxn, WkvT, kvbuf, 2048,  1024, 1024);
  transpose_v<<<dim3(8,32),256,0,stream>>>(kvbuf, vtbuf);
  bucket_kernel<<<64,256,0,stream>>>(ml, flag, counts, lists);
  attn_mfma5<<<dim3(128,32),512,0,stream>>>(qbuf, kvbuf, vtbuf, attn_o, counts, lists);
  gemm_bt<0><<<2048,256,0,stream>>>(attn_o, WoutT, out, 16384, 2048, 512);
}

// Round 10
// 198.021 us; speedup vs baseline: 1.3786x; 1.2198x over previous
//
#include <hip/hip_runtime.h>

typedef unsigned short u16;
typedef unsigned int u32;
typedef __attribute__((ext_vector_type(8))) short short8;
typedef __attribute__((ext_vector_type(4))) short short4_t;
typedef __attribute__((ext_vector_type(4))) float f32x4;

__device__ __forceinline__ float bf2f(u16 u){ return __uint_as_float(((u32)u)<<16); }
__device__ __forceinline__ u16 f2bf(float f){ u32 x = __float_as_uint(f); return (u16)((x + 0x7FFFu + ((x>>16)&1u)) >> 16); }

// ---------------- workspace layout (bytes) ----------------
#define OFF_FLAG   ((size_t)0)
#define OFF_COUNTS ((size_t)256)
#define OFF_LISTS  ((size_t)4096)                    // 32*4096 int
#define OFF_XN     ((size_t)(1<<20))
#define OFF_CTXN   (OFF_XN    + (size_t)67108864)
#define OFF_WQT    (OFF_CTXN  + (size_t)4194304)
#define OFF_WKVT   (OFF_WQT   + (size_t)2097152)
#define OFF_WOUTT  (OFF_WKVT  + (size_t)2097152)
#define OFF_Q      (OFF_WOUTT + (size_t)2097152)
#define OFF_KV     (OFF_Q     + (size_t)16777216)
#define OFF_ATTN   (OFF_KV    + (size_t)4194304)
#define OFF_VT     (OFF_ATTN  + (size_t)16777216)
#define WS_NEEDED  (OFF_VT    + (size_t)2097152)

// ---------------- fused LayerNorm -> bf16 (x, D=2048) ----------------
__global__ __launch_bounds__(256) void ln_x(const float* __restrict__ x, const float* __restrict__ w,
                                            const float* __restrict__ b, u16* __restrict__ out){
  constexpr int D = 2048, VEC = 8;
  int row = blockIdx.x;
  const float* xr = x + (size_t)row*D;
  int tid = threadIdx.x;
  float v[VEC];
  #pragma unroll
  for (int i=0;i<VEC;i+=4){
    f32x4 f = *(const f32x4*)(xr + tid*VEC + i);
    v[i]=f[0]; v[i+1]=f[1]; v[i+2]=f[2]; v[i+3]=f[3];
  }
  float s=0.f, sq=0.f;
  #pragma unroll
  for (int i=0;i<VEC;++i){ s += v[i]; sq += v[i]*v[i]; }
  #pragma unroll
  for (int off=32;off;off>>=1){ s += __shfl_xor(s,off,64); sq += __shfl_xor(sq,off,64); }
  __shared__ float red[8];
  int lane = tid&63, wid = tid>>6;
  if (lane==0){ red[wid]=s; red[4+wid]=sq; }
  __syncthreads();
  s  = red[0]+red[1]+red[2]+red[3];
  sq = red[4]+red[5]+red[6]+red[7];
  float mu = s/(float)D;
  float var = sq/(float)D - mu*mu;
  float rs = rsqrtf(var + 1e-5f);
  u16 o[VEC];
  #pragma unroll
  for (int i=0;i<VEC;i+=4){
    f32x4 wv = *(const f32x4*)(w + tid*VEC + i);
    f32x4 bv = *(const f32x4*)(b + tid*VEC + i);
    #pragma unroll
    for (int u=0;u<4;++u) o[i+u] = f2bf((v[i+u]-mu)*rs*wv[u] + bv[u]);
  }
  *(short8*)(out + (size_t)row*D + tid*8) = *(short8*)o;
}

// ---------------- merged: LN(ctx,D=1024) [0,2048) + weight transposes [2048,5120) + prep [5120] ----------------
__global__ __launch_bounds__(256) void ctx_prep(const float* __restrict__ ctx, const float* __restrict__ ncw,
                                                const float* __restrict__ ncb, u16* __restrict__ ctxn,
                                                const float* __restrict__ Wq, const float* __restrict__ Wkv,
                                                const float* __restrict__ Wout, u16* __restrict__ WqT,
                                                u16* __restrict__ WkvT, u16* __restrict__ WoutT,
                                                const int* __restrict__ ml32, int* __restrict__ flag,
                                                int* __restrict__ counts){
  int id = blockIdx.x, tid = threadIdx.x;
  __shared__ float red[8];
  __shared__ float t[32][33];
  __shared__ int nz;
  if (id < 2048){
    constexpr int D = 1024;
    const float* xr = ctx + (size_t)id*D;
    f32x4 f = *(const f32x4*)(xr + tid*4);
    float s = f[0]+f[1]+f[2]+f[3];
    float sq = f[0]*f[0]+f[1]*f[1]+f[2]*f[2]+f[3]*f[3];
    #pragma unroll
    for (int off=32;off;off>>=1){ s += __shfl_xor(s,off,64); sq += __shfl_xor(sq,off,64); }
    int lane = tid&63, wid = tid>>6;
    if (lane==0){ red[wid]=s; red[4+wid]=sq; }
    __syncthreads();
    s  = red[0]+red[1]+red[2]+red[3];
    sq = red[4]+red[5]+red[6]+red[7];
    float mu = s/(float)D;
    float var = sq/(float)D - mu*mu;
    float rs = rsqrtf(var + 1e-5f);
    f32x4 wv = *(const f32x4*)(ncw + tid*4);
    f32x4 bv = *(const f32x4*)(ncb + tid*4);
    u16 o[4];
    #pragma unroll
    for (int u=0;u<4;++u) o[u] = f2bf((f[u]-mu)*rs*wv[u] + bv[u]);
    *(short4_t*)(ctxn + (size_t)id*D + tid*4) = *(short4_t*)o;
  } else if (id < 5120){
    int wid2 = id - 2048;
    const float* in; u16* out; int K, N, tile, tx_n;
    if (wid2 < 1024)      { in=Wq;   out=WqT;   K=2048; N=512;  tile=wid2;      tx_n=16; }
    else if (wid2 < 2048) { in=Wkv;  out=WkvT;  K=1024; N=1024; tile=wid2-1024; tx_n=32; }
    else                  { in=Wout; out=WoutT; K=512;  N=2048; tile=wid2-2048; tx_n=64; }
    int n0 = (tile % tx_n)*32, k0 = (tile / tx_n)*32;
    int tx = tid & 31, ty = tid >> 5;
    #pragma unroll
    for (int r=0;r<32;r+=8) t[ty+r][tx] = in[(size_t)(k0+ty+r)*N + n0+tx];
    __syncthreads();
    #pragma unroll
    for (int r=0;r<32;r+=8) out[(size_t)(n0+ty+r)*K + k0+tx] = f2bf(t[tx][ty+r]);
  } else {
    // prep: zero bucket counts; detect int64 media_locations
    if (tid < 32) counts[tid] = 0;
    if (tid == 0) nz = 0;
    __syncthreads();
    if (tid < 128 && ml32[2*tid+1] != 0) atomicAdd(&nz, 1);
    __syncthreads();
    if (tid == 0) flag[0] = (nz == 0) ? 1 : 0;
  }
}

// ---------------- bf16 GEMM body: C[M,N] = A[M,K] * B^T  (B stored [N][K]) ----------------
// MODE: 0 = f32 out, 1 = bf16 out, 2 = bf16 out scaled by 0.125 (exact)
template<int MODE>
__device__ __forceinline__ void gemm_body(u16 (*lds)[2][128*32],
                                          const u16* __restrict__ A, const u16* __restrict__ B,
                                          void* __restrict__ Cv, int M, int N, int K, int wg0, int nwg){
  int tid = threadIdx.x, lane = tid&63, wid = tid>>6;
  int nbn = N>>7;
  int wg = wg0;
  int cpx = nwg>>3;                 // nwg %8==0 -> bijective XCD swizzle
  wg = (wg&7)*cpx + (wg>>3);
  int brow = wg/nbn, bcol = wg%nbn;

  auto stage = [&](int buf, int kt){
    #pragma unroll
    for (int i=0;i<2;++i){
      int cb = i*256 + wid*64;      // wave-uniform chunk base
      int c  = cb + lane;
      int row = c>>2, kc = c&3;
      const u16* ga = A + (size_t)(brow*128+row)*K + kt*32 + kc*8;
      __builtin_amdgcn_global_load_lds((const __attribute__((address_space(1))) u32*)ga,
          (__attribute__((address_space(3))) u32*)&lds[buf][0][cb*8], 16, 0, 0);
      const u16* gb = B + (size_t)(bcol*128+row)*K + kt*32 + kc*8;
      __builtin_amdgcn_global_load_lds((const __attribute__((address_space(1))) u32*)gb,
          (__attribute__((address_space(3))) u32*)&lds[buf][1][cb*8], 16, 0, 0);
    }
  };

  int wm = wid>>1, wn = wid&1;
  f32x4 acc[4][4] = {};
  int nkt = K>>5;
  stage(0,0);
  __syncthreads();
  for (int kt=0; kt<nkt; ++kt){
    int cur = kt&1;
    if (kt+1<nkt) stage(cur^1, kt+1);
    short8 af[4], bfr[4];
    int r = lane&15, kq = lane>>4;
    #pragma unroll
    for (int mi=0;mi<4;++mi) af[mi]  = *(const short8*)&lds[cur][0][(wm*64+mi*16+r)*32 + kq*8];
    #pragma unroll
    for (int ni=0;ni<4;++ni) bfr[ni] = *(const short8*)&lds[cur][1][(wn*64+ni*16+r)*32 + kq*8];
    #pragma unroll
    for (int mi=0;mi<4;++mi)
      #pragma unroll
      for (int ni=0;ni<4;++ni)
        acc[mi][ni] = __builtin_amdgcn_mfma_f32_16x16x32_bf16(af[mi], bfr[ni], acc[mi][ni], 0,0,0);
    __syncthreads();
  }
  int r4 = (lane>>4)*4, cc = lane&15;
  #pragma unroll
  for (int mi=0;mi<4;++mi)
    #pragma unroll
    for (int ni=0;ni<4;++ni)
      #pragma unroll
      for (int rr=0;rr<4;++rr){
        int row = brow*128 + wm*64 + mi*16 + r4 + rr;
        int col = bcol*128 + wn*64 + ni*16 + cc;
        float val = acc[mi][ni][rr];
        if (MODE==2) val *= 0.125f;
        if (MODE)  ((u16*)Cv)[(size_t)row*N+col] = f2bf(val);
        else       ((float*)Cv)[(size_t)row*N+col] = val;
      }
}

// out-GEMM: standalone (f32 dense)
__global__ __launch_bounds__(256) void gemm_out(const u16* __restrict__ A, const u16* __restrict__ B,
                                                float* __restrict__ C){
  __shared__ __align__(16) u16 lds[2][2][128*32];
  gemm_body<0>(lds, A, B, C, 16384, 2048, 512, blockIdx.x, gridDim.x);
}

// merged Q-GEMM [0,512) + KV-GEMM [512,640)
__global__ __launch_bounds__(256) void gemm_qkv(const u16* __restrict__ xn, const u16* __restrict__ WqT,
                                                u16* __restrict__ qbuf, const u16* __restrict__ ctxn,
                                                const u16* __restrict__ WkvT, u16* __restrict__ kvbuf){
  __shared__ __align__(16) u16 lds[2][2][128*32];
  if (blockIdx.x < 512) gemm_body<2>(lds, xn,   WqT,  qbuf,  16384, 512,  2048, blockIdx.x,     512);
  else                  gemm_body<1>(lds, ctxn, WkvT, kvbuf, 2048,  1024, 1024, blockIdx.x-512, 128);
}

// ---------------- merged: V transpose (all 256 blocks) + bucket (blocks 0..63) ----------------
// vt layout [bl][h][d][key]; bucket uses LDS histogram -> 32 spread global atomics per block.
__global__ __launch_bounds__(256) void tv_bucket(const u16* __restrict__ kvb, u16* __restrict__ vt,
                                                 const int* __restrict__ ml32, const int* __restrict__ flag,
                                                 int* __restrict__ counts, int* __restrict__ lists){
  int h = blockIdx.x, bl = blockIdx.y;
  int tid = threadIdx.x;
  int bid = bl*8 + h;               // 0..255
  __shared__ int lc[32], lbase[32];
  __shared__ u16 t[64][72];
  if (bid < 64){
    if (tid < 32) lc[tid] = 0;
    __syncthreads();
    int i = bid*256 + tid;          // 0..16383 = b*4096+s
    int loc = flag[0] ? ml32[2*i] : ml32[i];
    int blk = (i>>12)*8 + loc;
    int lpos = atomicAdd(&lc[blk], 1);
    __syncthreads();
    if (tid < 32 && lc[tid] > 0) lbase[tid] = atomicAdd(&counts[tid], lc[tid]);
    __syncthreads();
    lists[blk*4096 + lbase[blk] + lpos] = i & 4095;
    __syncthreads();
  }
  // V transpose part
  const u16* src = kvb + (size_t)(bl*64)*1024 + 512 + h*64;
  #pragma unroll
  for (int i=0;i<2;++i){
    int idx = i*2048 + tid*8;
    int key = idx>>6, d = idx&63;
    *(short8*)&t[key][d] = *(const short8*)(src + (size_t)key*1024 + d);
  }
  __syncthreads();
  u16* dst = vt + (size_t)(bl*8+h)*4096;
  #pragma unroll
  for (int i=0;i<2;++i){
    int idx = i*2048 + tid*8;
    int d = idx>>6, k0 = idx&63;
    u16 tmp[8];
    #pragma unroll
    for (int u=0;u<8;++u) tmp[u] = t[k0+u][d];
    *(short8*)(dst + d*64 + k0) = *(short8*)tmp;
  }
}

// ---------------- MFMA bucketed attention, v5 (unchanged from r9) ----------------
__global__ __launch_bounds__(512) void attn_mfma5(const u16* __restrict__ qb, const u16* __restrict__ kvb,
                                                  const u16* __restrict__ vt, u16* __restrict__ ob,
                                                  const int* __restrict__ counts, const int* __restrict__ lists){
  int bl = blockIdx.y, chunk = blockIdx.x;
  int cnt = counts[bl];
  int q0 = chunk*32;
  if (q0 >= cnt) return;
  int b = bl>>3, loc = bl&7;
  int tid = threadIdx.x, lane = tid&63, h = tid>>6;   // wave id == head
  __shared__ u16 qs[32][520];      // gathered Q rows -> per-wave P tile -> per-wave O tile
  int r = lane&15, g = lane>>4;

  const u16* kbase = kvb + (size_t)(b*512 + loc*64)*1024 + h*64;
  short8 kfr[4][2];
  #pragma unroll
  for (int nt=0;nt<4;++nt){
    const u16* krow = kbase + (size_t)(nt*16 + r)*1024;
    kfr[nt][0] = *(const short8*)(krow + g*8);
    kfr[nt][1] = *(const short8*)(krow + 32 + g*8);
  }
  const u16* vbase = vt + (size_t)(bl*8 + h)*4096;
  short8 vf[2][4];
  #pragma unroll
  for (int nt=0;nt<4;++nt){
    const u16* vrow = vbase + (size_t)(nt*16 + r)*64;
    vf[0][nt] = *(const short8*)(vrow + g*8);
    vf[1][nt] = *(const short8*)(vrow + 32 + g*8);
  }

  const u16* qbase = qb + (size_t)(b*4096)*512;
  #pragma unroll
  for (int p=0;p<4;++p){
    int c = p*512 + tid;
    int row = c>>6, cc = c&63;
    int qq = (q0 + row < cnt) ? lists[bl*4096 + q0 + row] : -1;
    if (qq >= 0)
      *(short8*)&qs[row][cc*8] = *(const short8*)(qbase + (size_t)qq*512 + cc*8);
  }
  __syncthreads();

  short8 qf[2][2];
  #pragma unroll
  for (int mt=0;mt<2;++mt){
    qf[mt][0] = *(const short8*)&qs[mt*16+r][h*64 + g*8];
    qf[mt][1] = *(const short8*)&qs[mt*16+r][h*64 + 32 + g*8];
  }

  f32x4 acc[2][4] = {};
  #pragma unroll
  for (int mt=0;mt<2;++mt)
    #pragma unroll
    for (int nt=0;nt<4;++nt){
      acc[mt][nt] = __builtin_amdgcn_mfma_f32_16x16x32_bf16(qf[mt][0], kfr[nt][0], acc[mt][nt], 0,0,0);
      acc[mt][nt] = __builtin_amdgcn_mfma_f32_16x16x32_bf16(qf[mt][1], kfr[nt][1], acc[mt][nt], 0,0,0);
    }

  #pragma unroll
  for (int mt=0;mt<2;++mt){
    #pragma unroll
    for (int rr=0;rr<4;++rr){
      float m = fmaxf(fmaxf(acc[mt][0][rr], acc[mt][1][rr]), fmaxf(acc[mt][2][rr], acc[mt][3][rr]));
      #pragma unroll
      for (int off=1;off<16;off<<=1) m = fmaxf(m, __shfl_xor(m, off));
      float e0 = __expf(acc[mt][0][rr]-m), e1 = __expf(acc[mt][1][rr]-m);
      float e2 = __expf(acc[mt][2][rr]-m), e3 = __expf(acc[mt][3][rr]-m);
      float sum = (e0+e1)+(e2+e3);
      #pragma unroll
      for (int off=1;off<16;off<<=1) sum += __shfl_xor(sum, off);
      float rs = 1.0f/sum;
      int row = mt*16 + g*4 + rr;
      qs[row][h*64 +  0 + r] = f2bf(e0*rs);
      qs[row][h*64 + 16 + r] = f2bf(e1*rs);
      qs[row][h*64 + 32 + r] = f2bf(e2*rs);
      qs[row][h*64 + 48 + r] = f2bf(e3*rs);
    }
  }

  f32x4 oacc[2][4] = {};
  #pragma unroll
  for (int mt=0;mt<2;++mt){
    short8 pa0 = *(const short8*)&qs[mt*16 + r][h*64 + g*8];
    short8 pa1 = *(const short8*)&qs[mt*16 + r][h*64 + 32 + g*8];
    #pragma unroll
    for (int nt=0;nt<4;++nt){
      oacc[mt][nt] = __builtin_amdgcn_mfma_f32_16x16x32_bf16(pa0, vf[0][nt], oacc[mt][nt], 0,0,0);
      oacc[mt][nt] = __builtin_amdgcn_mfma_f32_16x16x32_bf16(pa1, vf[1][nt], oacc[mt][nt], 0,0,0);
    }
  }

  #pragma unroll
  for (int mt=0;mt<2;++mt)
    #pragma unroll
    for (int rr=0;rr<4;++rr){
      int row = mt*16 + g*4 + rr;
      #pragma unroll
      for (int nt=0;nt<4;++nt)
        qs[row][h*64 + nt*16 + r] = f2bf(oacc[mt][nt][rr]);
    }
  __syncthreads();

  #pragma unroll
  for (int p=0;p<4;++p){
    int c = p*512 + tid;
    int row = c>>6, cc = c&63;
    int qq = (q0 + row < cnt) ? lists[bl*4096 + q0 + row] : -1;
    if (qq >= 0)
      *(short8*)(ob + ((size_t)(b*4096) + qq)*512 + cc*8) = *(const short8*)&qs[row][cc*8];
  }
}

extern "C" void kernel_launch(void* const* d_in, const int* in_sizes, int n_in,
                              void* d_out, int out_size, void* d_ws, size_t ws_size,
                              hipStream_t stream) {
  const float* x    = (const float*)d_in[0];
  const float* ctx  = (const float*)d_in[1];
  const int*   ml   = (const int*)d_in[2];
  const float* nw   = (const float*)d_in[3];
  const float* nb   = (const float*)d_in[4];
  const float* ncw  = (const float*)d_in[5];
  const float* ncb  = (const float*)d_in[6];
  const float* Wq   = (const float*)d_in[7];
  const float* Wkv  = (const float*)d_in[8];
  const float* Wout = (const float*)d_in[9];
  float* out = (float*)d_out;
  char* ws = (char*)d_ws;
  if (ws_size < WS_NEEDED) return;   // fail loudly (output stays poisoned)

  int* flag   = (int*)(ws + OFF_FLAG);
  int* counts = (int*)(ws + OFF_COUNTS);
  int* lists  = (int*)(ws + OFF_LISTS);
  u16* xn     = (u16*)(ws + OFF_XN);
  u16* ctxn   = (u16*)(ws + OFF_CTXN);
  u16* WqT    = (u16*)(ws + OFF_WQT);
  u16* WkvT   = (u16*)(ws + OFF_WKVT);
  u16* WoutT  = (u16*)(ws + OFF_WOUTT);
  u16* qbuf   = (u16*)(ws + OFF_Q);
  u16* kvbuf  = (u16*)(ws + OFF_KV);
  u16* attn_o = (u16*)(ws + OFF_ATTN);
  u16* vtbuf  = (u16*)(ws + OFF_VT);

  ln_x<<<16384,256,0,stream>>>(x, nw, nb, xn);
  ctx_prep<<<5121,256,0,stream>>>(ctx, ncw, ncb, ctxn, Wq, Wkv, Wout, WqT, WkvT, WoutT, ml, flag, counts);
  gemm_qkv<<<640,256,0,stream>>>(xn, WqT, qbuf, ctxn, WkvT, kvbuf);
  tv_bucket<<<dim3(8,32),256,0,stream>>>(kvbuf, vtbuf, ml, flag, counts, lists);
  attn_mfma5<<<dim3(128,32),512,0,stream>>>(qbuf, kvbuf, vtbuf, attn_o, counts, lists);
  gemm_out<<<2048,256,0,stream>>>(attn_o, WoutT, out);
}